// Round 1
// baseline (442.570 us; speedup 1.0000x reference)
//
#include <hip/hip_runtime.h>
#include <math.h>

typedef unsigned short u16;
typedef unsigned int u32;
typedef __bf16 bf16x8 __attribute__((ext_vector_type(8)));
typedef unsigned short us8 __attribute__((ext_vector_type(8)));
typedef unsigned short us4 __attribute__((ext_vector_type(4)));
typedef float f32x4 __attribute__((ext_vector_type(4)));

#define DEV __device__ __forceinline__

DEV u16 f2bf(float f) {
  u32 u = __builtin_bit_cast(u32, f);
  u += 0x7fff + ((u >> 16) & 1);
  return (u16)(u >> 16);
}

DEV bf16x8 ld_bf8(const u16* p) { return __builtin_bit_cast(bf16x8, *(const us8*)p); }

DEV void gload_lds16(const u16* g, u16* l) {
  __builtin_amdgcn_global_load_lds((const __attribute__((address_space(1))) void*)g,
                                   (__attribute__((address_space(3))) void*)l, 16, 0, 0);
}

DEV f32x4 mfma16(bf16x8 a, bf16x8 b, f32x4 c) {
  return __builtin_amdgcn_mfma_f32_16x16x32_bf16(a, b, c, 0, 0, 0);
}

// ---------------- prep kernels ----------------

__global__ void conv_bf16_kernel(const float* __restrict__ in, u16* __restrict__ out, int n4) {
  const int stride = gridDim.x * blockDim.x;
  for (int i = blockIdx.x * blockDim.x + threadIdx.x; i < n4; i += stride) {
    float4 v = ((const float4*)in)[i];
    us4 h; h[0] = f2bf(v.x); h[1] = f2bf(v.y); h[2] = f2bf(v.z); h[3] = f2bf(v.w);
    ((us4*)out)[i] = h;
  }
}

// in: K x N f32 (row-major)  ->  out: N x K bf16 (row-major) == B^T
__global__ __launch_bounds__(256) void transpose_bf16_kernel(
    const float* __restrict__ in, u16* __restrict__ out, int K, int N) {
  __shared__ float tile[32][33];
  const int nbk = K >> 5;
  const int bk = blockIdx.x % nbk, bn = blockIdx.x / nbk;
  const int r0 = bk << 5, c0 = bn << 5;
  const int t = threadIdx.x;
  {
    const int r = t >> 3, c4 = (t & 7) << 2;
    const float4 v = *(const float4*)(in + (size_t)(r0 + r) * N + c0 + c4);
    tile[r][c4] = v.x; tile[r][c4 + 1] = v.y; tile[r][c4 + 2] = v.z; tile[r][c4 + 3] = v.w;
  }
  __syncthreads();
  {
    const int oc = t >> 3, r4 = (t & 7) << 2;
    us4 h;
#pragma unroll
    for (int j = 0; j < 4; j++) h[j] = f2bf(tile[r4 + j][oc]);
    *(us4*)(out + (size_t)(c0 + oc) * K + r0 + r4) = h;
  }
}

// ---------------- GEMM ----------------
// C[M,N] = A[M,K] @ B[K,N], given A bf16 row-major and BT = B^T bf16 (N x K).
// MODE 0: q-heads out      : ob[b,n,l,d] (bf16)
// MODE 1: k-heads out      : ob[b,n,l,d] + ob2[b,n,d,l] (bf16)
// MODE 2: of = acc + res                               (f32)
// MODE 3: ob = gelu(acc + bias)                        (bf16)
// MODE 4: of = acc + bias + res                        (f32)
template <int MODE>
__global__ __launch_bounds__(256) void gemm128(
    const u16* __restrict__ A, const u16* __restrict__ BT,
    int M, int N, int K,
    u16* __restrict__ ob, u16* __restrict__ ob2,
    float* __restrict__ of,
    const float* __restrict__ res, const float* __restrict__ bias) {
  __shared__ u16 As[4096];
  __shared__ u16 Bs[4096];
  const int t = threadIdx.x;
  const int nbm = M >> 7;
  const int bm = blockIdx.x % nbm;
  const int bn = blockIdx.x / nbm;
  const int m0 = bm << 7, n0 = bn << 7;
  const int w = t >> 6, lane = t & 63;
  const int wr = w >> 1, wc = w & 1;
  const int lr = lane & 15, lk = (lane >> 4) << 3, lq = (lane >> 4) << 2;

  const u16* ap = A + (size_t)(m0 + (t >> 2)) * K + ((t & 3) << 3);
  const u16* bp = BT + (size_t)(n0 + (t >> 2)) * K + ((t & 3) << 3);
  u16* asd = &As[t << 3];
  u16* bsd = &Bs[t << 3];
  const size_t half = (size_t)64 * K;

  f32x4 acc[4][4];
#pragma unroll
  for (int i = 0; i < 4; i++)
#pragma unroll
    for (int j = 0; j < 4; j++) acc[i][j] = (f32x4){0.f, 0.f, 0.f, 0.f};

  for (int k0 = 0; k0 < K; k0 += 32) {
    gload_lds16(ap + k0, asd);
    gload_lds16(ap + half + k0, asd + 2048);
    gload_lds16(bp + k0, bsd);
    gload_lds16(bp + half + k0, bsd + 2048);
    __syncthreads();
    bf16x8 af[4], bfr[4];
#pragma unroll
    for (int i = 0; i < 4; i++) af[i] = ld_bf8(&As[(wr * 64 + i * 16 + lr) * 32 + lk]);
#pragma unroll
    for (int j = 0; j < 4; j++) bfr[j] = ld_bf8(&Bs[(wc * 64 + j * 16 + lr) * 32 + lk]);
#pragma unroll
    for (int i = 0; i < 4; i++)
#pragma unroll
      for (int j = 0; j < 4; j++) acc[i][j] = mfma16(af[i], bfr[j], acc[i][j]);
    __syncthreads();
  }

#pragma unroll
  for (int i = 0; i < 4; i++) {
    const int r0 = m0 + wr * 64 + i * 16 + lq;
#pragma unroll
    for (int j = 0; j < 4; j++) {
      const int c = n0 + wc * 64 + j * 16 + lr;
      if constexpr (MODE == 0 || MODE == 1) {
        const int bb_ = r0 >> 11;
        const int nn = c & 15, dd = c >> 4;
        us4 pk;
#pragma unroll
        for (int q = 0; q < 4; q++) {
          const int ll = (r0 + q) & 2047;
          u16 hv = f2bf(acc[i][j][q]);
          ob[(((size_t)(bb_ * 16 + nn) << 11) + ll) * 64 + dd] = hv;
          pk[q] = hv;
        }
        if constexpr (MODE == 1) {
          *(us4*)&ob2[((size_t)(bb_ * 16 + nn) * 64 + dd) * 2048 + (r0 & 2047)] = pk;
        }
      } else if constexpr (MODE == 2) {
#pragma unroll
        for (int q = 0; q < 4; q++) {
          const size_t idx = (size_t)(r0 + q) * N + c;
          of[idx] = acc[i][j][q] + res[idx];
        }
      } else if constexpr (MODE == 3) {
        const float bv = bias[c];
#pragma unroll
        for (int q = 0; q < 4; q++) {
          float u = acc[i][j][q] + bv;
          float gl = 0.5f * u * (1.f + erff(u * 0.70710678118f));
          ob[(size_t)(r0 + q) * N + c] = f2bf(gl);
        }
      } else {
        const float bv = bias[c];
#pragma unroll
        for (int q = 0; q < 4; q++) {
          const size_t idx = (size_t)(r0 + q) * N + c;
          of[idx] = acc[i][j][q] + bv + res[idx];
        }
      }
    }
  }
}

// ---------------- attention ----------------
// qh/kh: [b][n][l][d] bf16, kth: [b][n][d][l] bf16 ("V" == K per source bug)
// out ctxb: [b][l][d*16+n] bf16
__global__ __launch_bounds__(256) void attn_kernel(
    const u16* __restrict__ qh, const u16* __restrict__ kh,
    const u16* __restrict__ kth, u16* __restrict__ ctxb) {
  __shared__ u16 plds[4][2048];
  const int t = threadIdx.x, w = t >> 6, lane = t & 63;
  const int lr = lane & 15, lk = (lane >> 4) << 3, lq = (lane >> 4) << 2;
  const int bx = blockIdx.x;
  const int qi = bx & 15, hn = (bx >> 4) & 15, b = bx >> 8;
  const int l0 = qi * 128 + w * 32;
  const u16* qb = qh + (size_t)(b * 16 + hn) * 2048 * 64;
  const u16* kb = kh + (size_t)(b * 16 + hn) * 2048 * 64;
  const u16* ktb = kth + (size_t)(b * 16 + hn) * 64 * 2048;
  char* pb = (char*)&plds[w][0];

  bf16x8 qf[2][2];
#pragma unroll
  for (int ri = 0; ri < 2; ri++)
#pragma unroll
    for (int kk = 0; kk < 2; kk++)
      qf[ri][kk] = ld_bf8(qb + (size_t)(l0 + ri * 16 + lr) * 64 + kk * 32 + lk);

  float mrun[2][4], lrun[2][4];
  f32x4 o[2][4];
#pragma unroll
  for (int ri = 0; ri < 2; ri++) {
#pragma unroll
    for (int q = 0; q < 4; q++) { mrun[ri][q] = -1e30f; lrun[ri][q] = 0.f; }
#pragma unroll
    for (int dj = 0; dj < 4; dj++) o[ri][dj] = (f32x4){0.f, 0.f, 0.f, 0.f};
  }

  for (int m0 = 0; m0 < 2048; m0 += 64) {
    f32x4 s[2][4];
#pragma unroll
    for (int ri = 0; ri < 2; ri++)
#pragma unroll
      for (int mj = 0; mj < 4; mj++) s[ri][mj] = (f32x4){0.f, 0.f, 0.f, 0.f};
#pragma unroll
    for (int mj = 0; mj < 4; mj++) {
      const u16* kr = kb + (size_t)(m0 + mj * 16 + lr) * 64 + lk;
      bf16x8 kf0 = ld_bf8(kr);
      bf16x8 kf1 = ld_bf8(kr + 32);
#pragma unroll
      for (int ri = 0; ri < 2; ri++) {
        s[ri][mj] = mfma16(qf[ri][0], kf0, s[ri][mj]);
        s[ri][mj] = mfma16(qf[ri][1], kf1, s[ri][mj]);
      }
    }
    // online softmax over the 64 key columns of this tile (rows spread over 16-lane groups)
#pragma unroll
    for (int ri = 0; ri < 2; ri++) {
#pragma unroll
      for (int q = 0; q < 4; q++) {
        float s0 = s[ri][0][q] * 0.125f, s1 = s[ri][1][q] * 0.125f;
        float s2 = s[ri][2][q] * 0.125f, s3 = s[ri][3][q] * 0.125f;
        float tm = fmaxf(fmaxf(s0, s1), fmaxf(s2, s3));
        tm = fmaxf(tm, __shfl_xor(tm, 1));
        tm = fmaxf(tm, __shfl_xor(tm, 2));
        tm = fmaxf(tm, __shfl_xor(tm, 4));
        tm = fmaxf(tm, __shfl_xor(tm, 8));
        const float mold = mrun[ri][q];
        const float mnew = fmaxf(mold, tm);
        const float al = __expf(mold - mnew);
        float p0 = __expf(s0 - mnew), p1 = __expf(s1 - mnew);
        float p2 = __expf(s2 - mnew), p3 = __expf(s3 - mnew);
        float ts = p0 + p1 + p2 + p3;
        ts += __shfl_xor(ts, 1);
        ts += __shfl_xor(ts, 2);
        ts += __shfl_xor(ts, 4);
        ts += __shfl_xor(ts, 8);
        lrun[ri][q] = lrun[ri][q] * al + ts;
        mrun[ri][q] = mnew;
#pragma unroll
        for (int dj = 0; dj < 4; dj++) o[ri][dj][q] *= al;
        const int rr = ri * 16 + lq + q;
        const int swz = (rr & 7) << 4;
        const int rb2 = rr * 128;
        *(u16*)(pb + ((rb2 + (0 * 16 + lr) * 2) ^ swz)) = f2bf(p0);
        *(u16*)(pb + ((rb2 + (1 * 16 + lr) * 2) ^ swz)) = f2bf(p1);
        *(u16*)(pb + ((rb2 + (2 * 16 + lr) * 2) ^ swz)) = f2bf(p2);
        *(u16*)(pb + ((rb2 + (3 * 16 + lr) * 2) ^ swz)) = f2bf(p3);
      }
    }
    // P D-layout -> A-layout via per-wave LDS (same-wave DS ops are ordered)
    bf16x8 pa[2][2];
#pragma unroll
    for (int ri = 0; ri < 2; ri++) {
      const int rr = ri * 16 + lr;
      const int swz = (rr & 7) << 4;
#pragma unroll
      for (int mk = 0; mk < 2; mk++) {
        pa[ri][mk] = __builtin_bit_cast(
            bf16x8, *(const us8*)(pb + ((rr * 128 + (mk * 32 + lk) * 2) ^ swz)));
      }
    }
    // PV: ctx += P @ K  (B-operand from transposed K)
#pragma unroll
    for (int dj = 0; dj < 4; dj++) {
      const u16* kt = ktb + (size_t)(dj * 16 + lr) * 2048 + m0 + lk;
      bf16x8 v0 = ld_bf8(kt);
      bf16x8 v1 = ld_bf8(kt + 32);
#pragma unroll
      for (int ri = 0; ri < 2; ri++) {
        o[ri][dj] = mfma16(pa[ri][0], v0, o[ri][dj]);
        o[ri][dj] = mfma16(pa[ri][1], v1, o[ri][dj]);
      }
    }
  }

#pragma unroll
  for (int ri = 0; ri < 2; ri++) {
#pragma unroll
    for (int q = 0; q < 4; q++) {
      const float inv = 1.f / lrun[ri][q];
      const int ll = l0 + ri * 16 + lq + q;
#pragma unroll
      for (int dj = 0; dj < 4; dj++) {
        const int d = dj * 16 + lr;
        ctxb[((size_t)b * 2048 + ll) * 1024 + d * 16 + hn] = f2bf(o[ri][dj][q] * inv);
      }
    }
  }
}

// ---------------- layernorm ----------------
__global__ __launch_bounds__(256) void ln_kernel(
    const float* __restrict__ in, const float* __restrict__ gamma,
    const float* __restrict__ beta, float* __restrict__ o32, u16* __restrict__ o16) {
  __shared__ float red[8];
  const int row = blockIdx.x, t = threadIdx.x;
  const float4 v = ((const float4*)(in + (size_t)row * 1024))[t];
  float s = v.x + v.y + v.z + v.w;
  float ss = v.x * v.x + v.y * v.y + v.z * v.z + v.w * v.w;
#pragma unroll
  for (int off = 1; off < 64; off <<= 1) {
    s += __shfl_xor(s, off);
    ss += __shfl_xor(ss, off);
  }
  if ((t & 63) == 0) { red[t >> 6] = s; red[4 + (t >> 6)] = ss; }
  __syncthreads();
  const float st = red[0] + red[1] + red[2] + red[3];
  const float sst = red[4] + red[5] + red[6] + red[7];
  const float mean = st * (1.f / 1024.f);
  const float var = sst * (1.f / 1024.f) - mean * mean;
  const float rs = rsqrtf(var + 1e-5f);
  const float4 gv = ((const float4*)gamma)[t];
  const float4 bv = ((const float4*)beta)[t];
  float4 ov;
  ov.x = (v.x - mean) * rs * gv.x + bv.x;
  ov.y = (v.y - mean) * rs * gv.y + bv.y;
  ov.z = (v.z - mean) * rs * gv.z + bv.z;
  ov.w = (v.w - mean) * rs * gv.w + bv.w;
  ((float4*)(o32 + (size_t)row * 1024))[t] = ov;
  if (o16) {
    us4 h;
    h[0] = f2bf(ov.x); h[1] = f2bf(ov.y); h[2] = f2bf(ov.z); h[3] = f2bf(ov.w);
    *(us4*)(o16 + (size_t)row * 1024 + t * 4) = h;
  }
}

// ---------------- launch ----------------
extern "C" void kernel_launch(void* const* d_in, const int* in_sizes, int n_in,
                              void* d_out, int out_size, void* d_ws, size_t ws_size,
                              hipStream_t stream) {
  const float* x   = (const float*)d_in[0];
  const float* wq  = (const float*)d_in[1];
  const float* wk  = (const float*)d_in[2];
  const float* wo  = (const float*)d_in[3];
  const float* g1  = (const float*)d_in[4];
  const float* b1  = (const float*)d_in[5];
  const float* w1  = (const float*)d_in[6];
  const float* bb1 = (const float*)d_in[7];
  const float* w2  = (const float*)d_in[8];
  const float* bb2 = (const float*)d_in[9];
  const float* g2  = (const float*)d_in[10];
  const float* b2  = (const float*)d_in[11];

  char* ws = (char*)d_ws;
  const size_t MB = 1ull << 20;
  u16* xb   = (u16*)(ws + 0 * MB);    // 8 MB   [prep -> gemm1]
  u16* qhp  = (u16*)(ws + 8 * MB);    // 8 MB   [gemm1 -> attn]
  u16* khp  = (u16*)(ws + 16 * MB);   // 8 MB
  u16* kthp = (u16*)(ws + 24 * MB);   // 8 MB
  u16* ctxb = (u16*)(ws + 32 * MB);   // 8 MB   [attn -> gemm2]
  u16* tbuf = (u16*)(ws + 8 * MB);    // 32 MB  overlay (gemm3 -> gemm4)
  float* rbuf = (float*)(ws + 40 * MB);  // 16 MB
  float* hbuf = (float*)(ws + 56 * MB);  // 16 MB
  u16* hb   = (u16*)(ws + 72 * MB);   // 8 MB
  u16* wqT  = (u16*)(ws + 80 * MB);   // 2 MB
  u16* wkT  = (u16*)(ws + 82 * MB);   // 2 MB
  u16* woT  = (u16*)(ws + 84 * MB);   // 2 MB
  u16* w1T  = (u16*)(ws + 86 * MB);   // 8 MB
  u16* w2T  = (u16*)(ws + 94 * MB);   // 8 MB  (end: 102 MB)

  // prep
  conv_bf16_kernel<<<1024, 256, 0, stream>>>(x, xb, 1048576);
  transpose_bf16_kernel<<<32 * 32, 256, 0, stream>>>(wq, wqT, 1024, 1024);
  transpose_bf16_kernel<<<32 * 32, 256, 0, stream>>>(wk, wkT, 1024, 1024);
  transpose_bf16_kernel<<<32 * 32, 256, 0, stream>>>(wo, woT, 1024, 1024);
  transpose_bf16_kernel<<<32 * 128, 256, 0, stream>>>(w1, w1T, 1024, 4096);
  transpose_bf16_kernel<<<128 * 32, 256, 0, stream>>>(w2, w2T, 4096, 1024);

  // q/k projections (head-scatter epilogues)
  gemm128<0><<<32 * 8, 256, 0, stream>>>(xb, wqT, 4096, 1024, 1024, qhp, nullptr, nullptr, nullptr, nullptr);
  gemm128<1><<<32 * 8, 256, 0, stream>>>(xb, wkT, 4096, 1024, 1024, khp, kthp, nullptr, nullptr, nullptr);

  // attention (V := K per source bug)
  attn_kernel<<<512, 256, 0, stream>>>(qhp, khp, kthp, ctxb);

  // attn_out @ wo + x  ->  rbuf ; LN1 -> hbuf (f32) + hb (bf16)
  gemm128<2><<<32 * 8, 256, 0, stream>>>(ctxb, woT, 4096, 1024, 1024, nullptr, nullptr, rbuf, x, nullptr);
  ln_kernel<<<4096, 256, 0, stream>>>(rbuf, g1, b1, hbuf, hb);

  // FFN
  gemm128<3><<<32 * 32, 256, 0, stream>>>(hb, w1T, 4096, 4096, 1024, tbuf, nullptr, nullptr, nullptr, bb1);
  gemm128<4><<<32 * 8, 256, 0, stream>>>(tbuf, w2T, 4096, 1024, 4096, nullptr, nullptr, rbuf, hbuf, bb2);
  ln_kernel<<<4096, 256, 0, stream>>>(rbuf, g2, b2, (float*)d_out, nullptr);
}